// Round 4
// baseline (1337.363 us; speedup 1.0000x reference)
//
#include <hip/hip_runtime.h>
#include <hip/hip_bf16.h>

typedef __attribute__((ext_vector_type(4))) float f32x4;
typedef __attribute__((ext_vector_type(8))) short bf16x8;

#define SCALE_QK 0.044194173824159216f  // 512^-0.5

static __device__ __forceinline__ short f2bf(float f) {
  union { float f; unsigned u; } c; c.f = f;
  unsigned lsb = (c.u >> 16) & 1u;
  c.u += 0x7fffu + lsb;              // RNE
  return (short)(c.u >> 16);
}

static __device__ __forceinline__ void load_lds16(const void* g, void* l) {
  __builtin_amdgcn_global_load_lds(
      (const __attribute__((address_space(1))) void*)g,
      (__attribute__((address_space(3))) void*)l, 16, 0, 0);
}

// ---------------------------------------------------------------------------
// slots = mu + exp(logsigma) * noise     (524288 elems)
__global__ __launch_bounds__(256) void slot_init_kernel(
    const float* __restrict__ noise, const float* __restrict__ mu,
    const float* __restrict__ logsig, float* __restrict__ slots)
{
  int i = blockIdx.x * 256 + threadIdx.x;
  int d = i & 511;
  slots[i] = mu[d] + expf(logsig[d]) * noise[i];
}

// f32 -> bf16 cast (n multiple of 1024)
__global__ __launch_bounds__(256) void cast_kernel(
    const float* __restrict__ src, short* __restrict__ dst, int n)
{
  int i = (blockIdx.x * 256 + threadIdx.x) * 4;
  if (i < n) {
    float4 v = *(const float4*)(src + i);
    short4 o = make_short4(f2bf(v.x), f2bf(v.y), f2bf(v.z), f2bf(v.w));
    *(short4*)(dst + i) = o;
  }
}

// ---------------------------------------------------------------------------
// Row LayerNorm (D=512), one wave per row, writes bf16; optional raw bf16 cast.
__global__ __launch_bounds__(256) void ln_kernel(
    const float* __restrict__ X, const float* __restrict__ gamma,
    const float* __restrict__ beta, short* __restrict__ Y,
    short* __restrict__ rawY, int rows)
{
  const int wave = threadIdx.x >> 6, lane = threadIdx.x & 63;
  const int row = blockIdx.x * 4 + wave;
  if (row >= rows) return;
  const float4* xr = (const float4*)(X + (size_t)row * 512);
  float4 a = xr[lane];
  float4 b = xr[64 + lane];
  float s = a.x + a.y + a.z + a.w + b.x + b.y + b.z + b.w;
  float q = a.x*a.x + a.y*a.y + a.z*a.z + a.w*a.w
          + b.x*b.x + b.y*b.y + b.z*b.z + b.w*b.w;
  #pragma unroll
  for (int off = 32; off; off >>= 1) {
    s += __shfl_xor(s, off);
    q += __shfl_xor(q, off);
  }
  const float mean = s * (1.f / 512.f);
  const float rstd = rsqrtf(q * (1.f / 512.f) - mean * mean + 1e-5f);
  const float4 g0 = ((const float4*)gamma)[lane];
  const float4 g1 = ((const float4*)gamma)[64 + lane];
  const float4 e0 = ((const float4*)beta)[lane];
  const float4 e1 = ((const float4*)beta)[64 + lane];
  short4 o0 = make_short4(
      f2bf((a.x - mean) * rstd * g0.x + e0.x),
      f2bf((a.y - mean) * rstd * g0.y + e0.y),
      f2bf((a.z - mean) * rstd * g0.z + e0.z),
      f2bf((a.w - mean) * rstd * g0.w + e0.w));
  short4 o1 = make_short4(
      f2bf((b.x - mean) * rstd * g1.x + e1.x),
      f2bf((b.y - mean) * rstd * g1.y + e1.y),
      f2bf((b.z - mean) * rstd * g1.z + e1.z),
      f2bf((b.w - mean) * rstd * g1.w + e1.w));
  ((short4*)(Y + (size_t)row * 512))[lane] = o0;
  ((short4*)(Y + (size_t)row * 512))[64 + lane] = o1;
  if (rawY) {
    short4 r0 = make_short4(f2bf(a.x), f2bf(a.y), f2bf(a.z), f2bf(a.w));
    short4 r1 = make_short4(f2bf(b.x), f2bf(b.y), f2bf(b.z), f2bf(b.w));
    ((short4*)(rawY + (size_t)row * 512))[lane] = r0;
    ((short4*)(rawY + (size_t)row * 512))[64 + lane] = r1;
  }
}

// ---------------------------------------------------------------------------
// C[M,N] = A[M,K](bf16) @ W[N,K]^T(bf16) + bias, 128x128 tile, BK=32, 4 waves.
// MODE 0: f32 out        MODE 1: bf16 out        MODE 2: relu -> bf16 out
// MODE 3: f32 out + resid add     MODE 4: kv split (k bf16 / vT bf16 scatter)
template <int MODE>
__global__ __launch_bounds__(256) void gemm_bt(
    const short* __restrict__ A, const short* __restrict__ W,
    const float* __restrict__ bias,
    float* __restrict__ Cf, short* __restrict__ Cb, short* __restrict__ Cb2,
    const float* __restrict__ resid, int M, int N, int K)
{
  __shared__ short As[4096];
  __shared__ short Bs[4096];
  const int tid = threadIdx.x;
  const int wave = tid >> 6, lane = tid & 63;
  const int bn = blockIdx.x, bm = blockIdx.y;
  const int wr = wave >> 1, wc = wave & 1;

  f32x4 acc[4][4];
  #pragma unroll
  for (int i = 0; i < 4; i++)
    #pragma unroll
    for (int j = 0; j < 4; j++)
      acc[i][j] = (f32x4){0.f, 0.f, 0.f, 0.f};

  const int c0 = wave * 64 + lane;
  const int c1 = c0 + 256;
  const int rA0 = c0 >> 2, o0 = (c0 & 3) << 3;
  const int rA1 = c1 >> 2, o1 = (c1 & 3) << 3;
  const short* gA0 = A + (size_t)(bm * 128 + rA0) * K + o0;
  const short* gA1 = A + (size_t)(bm * 128 + rA1) * K + o1;
  const short* gW0 = W + (size_t)(bn * 128 + rA0) * K + o0;
  const short* gW1 = W + (size_t)(bn * 128 + rA1) * K + o1;
  short* lA0 = As + c0 * 8;
  short* lA1 = As + c1 * 8;
  short* lB0 = Bs + c0 * 8;
  short* lB1 = Bs + c1 * 8;

  const int r = lane & 15, ks = (lane >> 4) << 3;

  for (int k0 = 0; k0 < K; k0 += 32) {
    load_lds16(gA0 + k0, lA0);
    load_lds16(gA1 + k0, lA1);
    load_lds16(gW0 + k0, lB0);
    load_lds16(gW1 + k0, lB1);
    __syncthreads();
    bf16x8 af[4], bfr[4];
    #pragma unroll
    for (int i = 0; i < 4; i++)
      af[i] = *(const bf16x8*)&As[(wr * 64 + i * 16 + r) * 32 + ks];
    #pragma unroll
    for (int j = 0; j < 4; j++)
      bfr[j] = *(const bf16x8*)&Bs[(wc * 64 + j * 16 + r) * 32 + ks];
    #pragma unroll
    for (int i = 0; i < 4; i++)
      #pragma unroll
      for (int j = 0; j < 4; j++)
        acc[i][j] = __builtin_amdgcn_mfma_f32_16x16x32_bf16(af[i], bfr[j],
                                                            acc[i][j], 0, 0, 0);
    __syncthreads();
  }

  const int r4 = (lane >> 4) << 2;
  const int ci = lane & 15;
  #pragma unroll
  for (int i = 0; i < 4; i++) {
    #pragma unroll
    for (int j = 0; j < 4; j++) {
      const int col = bn * 128 + wc * 64 + j * 16 + ci;
      const float bv = bias[col];
      #pragma unroll
      for (int rr = 0; rr < 4; rr++) {
        const int row = bm * 128 + wr * 64 + i * 16 + r4 + rr;
        float v = acc[i][j][rr] + bv;
        if (MODE == 2) v = fmaxf(v, 0.f);
        if (MODE == 3) v += resid[(size_t)row * N + col];
        if (MODE == 0 || MODE == 3) {
          Cf[(size_t)row * N + col] = v;
        } else if (MODE == 1 || MODE == 2) {
          Cb[(size_t)row * N + col] = f2bf(v);
        } else {  // MODE 4: cols [0,512) -> k_bf [B*N][512]; [512,1024) -> vT [B][512][1024]
          if (col < 512) {
            Cb[(size_t)row * 512 + col] = f2bf(v);
          } else {
            const int b = row >> 10, n = row & 1023, d = col - 512;
            Cb2[((size_t)b * 512 + d) * 1024 + n] = f2bf(v);
          }
        }
      }
    }
  }
}

// ---------------------------------------------------------------------------
// Per-batch fused attention: dots = k @ q^T (MFMA), softmax over slots (axis
// of size 8), +EPS, normalize over n, updates^T = vT @ attn^T (MFMA).
__global__ __launch_bounds__(1024) void attn_kernel(
    const short* __restrict__ q_bf,   // [B*8][512]
    const short* __restrict__ k_bf,   // [B*1024][512]
    const short* __restrict__ vT,     // [B][512][1024]
    short* __restrict__ upd_bf)       // [B*8][512]
{
  __shared__ short qs[16 * 520];      // padded, rows 8..15 zero
  __shared__ float at[1024 * 9];      // padded [n][slot]
  __shared__ float red[16 * 8];
  __shared__ float dinv[8];
  const int b = blockIdx.x;
  const int tid = threadIdx.x;
  const int wave = tid >> 6, lane = tid & 63;
  const int rlo = lane & 15, kg = lane >> 4;

  for (int i = tid; i < 16 * 520; i += 1024) qs[i] = 0;
  __syncthreads();
  for (int i = tid; i < 4096; i += 1024)
    qs[(i >> 9) * 520 + (i & 511)] = q_bf[(size_t)b * 4096 + i];
  __syncthreads();

  // phase 1: dots^T[n][i], wave handles n in [wave*64, wave*64+64)
  {
    f32x4 acc[4];
    #pragma unroll
    for (int m = 0; m < 4; m++) acc[m] = (f32x4){0.f, 0.f, 0.f, 0.f};
    const short* kb = k_bf + (size_t)b * 1024 * 512;
    for (int d0 = 0; d0 < 512; d0 += 32) {
      bf16x8 bq = *(const bf16x8*)&qs[rlo * 520 + d0 + (kg << 3)];
      #pragma unroll
      for (int mf = 0; mf < 4; mf++) {
        const short* kp = kb + (size_t)(wave * 64 + mf * 16 + rlo) * 512 + d0 + (kg << 3);
        bf16x8 ak = *(const bf16x8*)kp;
        acc[mf] = __builtin_amdgcn_mfma_f32_16x16x32_bf16(ak, bq, acc[mf], 0, 0, 0);
      }
    }
    if (rlo < 8) {
      #pragma unroll
      for (int mf = 0; mf < 4; mf++)
        #pragma unroll
        for (int rr = 0; rr < 4; rr++)
          at[(wave * 64 + mf * 16 + kg * 4 + rr) * 9 + rlo] = acc[mf][rr] * SCALE_QK;
    }
  }
  __syncthreads();

  // softmax over slots for n = tid, then +EPS, then per-slot sum over n
  float val[8];
  {
    float m = -1e30f;
    #pragma unroll
    for (int i = 0; i < 8; i++) { val[i] = at[tid * 9 + i]; m = fmaxf(m, val[i]); }
    float s = 0.f;
    #pragma unroll
    for (int i = 0; i < 8; i++) { val[i] = __expf(val[i] - m); s += val[i]; }
    float inv = 1.f / s;
    #pragma unroll
    for (int i = 0; i < 8; i++) val[i] = val[i] * inv + 1e-8f;
    #pragma unroll
    for (int i = 0; i < 8; i++) {
      float v = val[i];
      #pragma unroll
      for (int off = 32; off; off >>= 1) v += __shfl_xor(v, off);
      if (lane == 0) red[wave * 8 + i] = v;
    }
  }
  __syncthreads();
  if (tid < 8) {
    float s = 0.f;
    #pragma unroll
    for (int w = 0; w < 16; w++) s += red[w * 8 + tid];
    dinv[tid] = 1.f / s;
  }
  __syncthreads();
  #pragma unroll
  for (int i = 0; i < 8; i++) at[tid * 9 + i] = val[i] * dinv[i];
  __syncthreads();

  // phase 2: updates^T[d][i] = sum_n vT[d][n] * attn[i][n]; wave owns 32 d's
  {
    f32x4 acc[2];
    acc[0] = (f32x4){0.f, 0.f, 0.f, 0.f};
    acc[1] = (f32x4){0.f, 0.f, 0.f, 0.f};
    const short* vb = vT + (size_t)b * 512 * 1024;
    for (int n0 = 0; n0 < 1024; n0 += 32) {
      bf16x8 bfr = {0, 0, 0, 0, 0, 0, 0, 0};
      if (rlo < 8) {
        #pragma unroll
        for (int e = 0; e < 8; e++)
          ((short*)&bfr)[e] = f2bf(at[(n0 + (kg << 3) + e) * 9 + rlo]);
      }
      #pragma unroll
      for (int mf = 0; mf < 2; mf++) {
        const short* vp = vb + (size_t)(wave * 32 + mf * 16 + rlo) * 1024 + n0 + (kg << 3);
        bf16x8 av = *(const bf16x8*)vp;
        acc[mf] = __builtin_amdgcn_mfma_f32_16x16x32_bf16(av, bfr, acc[mf], 0, 0, 0);
      }
    }
    if (rlo < 8) {
      #pragma unroll
      for (int mf = 0; mf < 2; mf++)
        #pragma unroll
        for (int rr = 0; rr < 4; rr++) {
          const int d = wave * 32 + mf * 16 + kg * 4 + rr;
          upd_bf[((size_t)b * 8 + rlo) * 512 + d] = f2bf(acc[mf][rr]);
        }
    }
  }
}

// ---------------------------------------------------------------------------
// GRU gate: slots = (1-z)*tanh(xn + r*hn) + z*prev   (524288 elems)
__global__ __launch_bounds__(256) void gru_gate_kernel(
    const float* __restrict__ xg, const float* __restrict__ hg,
    float* __restrict__ slots)
{
  int idx = blockIdx.x * 256 + threadIdx.x;
  int row = idx >> 9, col = idx & 511;
  size_t base = (size_t)row * 1536;
  float xr = xg[base + col], xz = xg[base + 512 + col], xn = xg[base + 1024 + col];
  float hr = hg[base + col], hz = hg[base + 512 + col], hn = hg[base + 1024 + col];
  float rg = 1.f / (1.f + __expf(-(xr + hr)));
  float zg = 1.f / (1.f + __expf(-(xz + hz)));
  float nn = tanhf(xn + rg * hn);
  float prev = slots[idx];
  slots[idx] = (1.f - zg) * nn + zg * prev;
}

// ---------------------------------------------------------------------------
extern "C" void kernel_launch(void* const* d_in, const int* in_sizes, int n_in,
                              void* d_out, int out_size, void* d_ws, size_t ws_size,
                              hipStream_t stream) {
  const float* inputs         = (const float*)d_in[0];
  const float* slot_noise     = (const float*)d_in[1];
  const float* slots_mu       = (const float*)d_in[2];
  const float* slots_logsigma = (const float*)d_in[3];
  const float* g_in  = (const float*)d_in[4];
  const float* be_in = (const float*)d_in[5];
  const float* g_sl  = (const float*)d_in[6];
  const float* be_sl = (const float*)d_in[7];
  const float* g_ff  = (const float*)d_in[8];
  const float* be_ff = (const float*)d_in[9];
  const float* Wq   = (const float*)d_in[10];
  const float* bq   = (const float*)d_in[11];
  const float* Wk   = (const float*)d_in[12];
  const float* bk   = (const float*)d_in[13];
  const float* Wv   = (const float*)d_in[14];
  const float* bv   = (const float*)d_in[15];
  const float* W_ih = (const float*)d_in[16];
  const float* b_ih = (const float*)d_in[17];
  const float* W_hh = (const float*)d_in[18];
  const float* b_hh = (const float*)d_in[19];
  const float* W1   = (const float*)d_in[20];
  const float* b1   = (const float*)d_in[21];
  const float* W2   = (const float*)d_in[22];
  const float* b2   = (const float*)d_in[23];

  size_t off = 0;
  auto alloc = [&](size_t bytes) -> void* {
    void* p = (char*)d_ws + off;
    off += (bytes + 255) & ~(size_t)255;
    return p;
  };
  short* x_bf  = (short*)alloc(131072ULL * 512 * 2);  // LN(inputs) bf16
  short* k_bf  = (short*)alloc(131072ULL * 512 * 2);  // k [B*N][512]
  short* vT    = (short*)alloc(131072ULL * 512 * 2);  // v^T [B][512][1024]
  short* Wkv_b = (short*)alloc(1024ULL * 512 * 2);
  short* Wq_b  = (short*)alloc(512ULL * 512 * 2);
  short* Wih_b = (short*)alloc(1536ULL * 512 * 2);
  short* Whh_b = (short*)alloc(1536ULL * 512 * 2);
  short* W1_b  = (short*)alloc(512ULL * 512 * 2);
  short* W2_b  = (short*)alloc(512ULL * 512 * 2);
  float* biaskv = (float*)alloc(1024 * 4);
  float* slots  = (float*)alloc(524288ULL * 4);
  short* sln_b  = (short*)alloc(524288ULL * 2);
  short* prev_b = (short*)alloc(524288ULL * 2);
  short* p_b    = (short*)alloc(524288ULL * 2);
  short* t1_b   = (short*)alloc(524288ULL * 2);
  short* q_b    = (short*)alloc(524288ULL * 2);
  short* upd_b  = (short*)alloc(524288ULL * 2);
  float* xg     = (float*)alloc(1024ULL * 1536 * 4);
  float* hg     = (float*)alloc(1024ULL * 1536 * 4);

  // Safety: if the harness workspace is smaller than our footprint, do not
  // launch anything (clean absmax-fail instead of a device memory fault).
  if (off > ws_size) return;

  // prep: bias concat + weight casts + slot init
  hipMemcpyAsync(biaskv, bk, 512 * 4, hipMemcpyDeviceToDevice, stream);
  hipMemcpyAsync(biaskv + 512, bv, 512 * 4, hipMemcpyDeviceToDevice, stream);
  cast_kernel<<<256, 256, 0, stream>>>(Wk, Wkv_b, 262144);
  cast_kernel<<<256, 256, 0, stream>>>(Wv, Wkv_b + 262144, 262144);
  cast_kernel<<<256, 256, 0, stream>>>(Wq, Wq_b, 262144);
  cast_kernel<<<768, 256, 0, stream>>>(W_ih, Wih_b, 786432);
  cast_kernel<<<768, 256, 0, stream>>>(W_hh, Whh_b, 786432);
  cast_kernel<<<256, 256, 0, stream>>>(W1, W1_b, 262144);
  cast_kernel<<<256, 256, 0, stream>>>(W2, W2_b, 262144);
  slot_init_kernel<<<2048, 256, 0, stream>>>(slot_noise, slots_mu, slots_logsigma, slots);

  // LN(inputs) -> x_bf
  ln_kernel<<<32768, 256, 0, stream>>>(inputs, g_in, be_in, x_bf, nullptr, 131072);

  // k,v projections (fused): [131072,512] @ [1024,512]^T
  gemm_bt<4><<<dim3(8, 1024), 256, 0, stream>>>(
      x_bf, Wkv_b, biaskv, nullptr, k_bf, vT, nullptr, 131072, 1024, 512);

  for (int it = 0; it < 3; ++it) {
    // s = LN(slots) -> sln_b ; prev_b = bf16(slots)
    ln_kernel<<<256, 256, 0, stream>>>(slots, g_sl, be_sl, sln_b, prev_b, 1024);
    // q = s @ Wq^T + bq -> bf16
    gemm_bt<1><<<dim3(4, 8), 256, 0, stream>>>(
        sln_b, Wq_b, bq, nullptr, q_b, nullptr, nullptr, 1024, 512, 512);
    // attention -> updates bf16
    attn_kernel<<<128, 1024, 0, stream>>>(q_b, k_bf, vT, upd_b);
    // GRU gates
    gemm_bt<0><<<dim3(12, 8), 256, 0, stream>>>(
        upd_b, Wih_b, b_ih, xg, nullptr, nullptr, nullptr, 1024, 1536, 512);
    gemm_bt<0><<<dim3(12, 8), 256, 0, stream>>>(
        prev_b, Whh_b, b_hh, hg, nullptr, nullptr, nullptr, 1024, 1536, 512);
    gru_gate_kernel<<<2048, 256, 0, stream>>>(xg, hg, slots);
    // FF: slots += relu(LN(slots)@W1^T + b1)@W2^T + b2
    ln_kernel<<<256, 256, 0, stream>>>(slots, g_ff, be_ff, p_b, nullptr, 1024);
    gemm_bt<2><<<dim3(4, 8), 256, 0, stream>>>(
        p_b, W1_b, b1, nullptr, t1_b, nullptr, nullptr, 1024, 512, 512);
    gemm_bt<3><<<dim3(4, 8), 256, 0, stream>>>(
        t1_b, W2_b, b2, slots, nullptr, nullptr, slots, 1024, 512, 512);
  }

  hipMemcpyAsync(d_out, slots, 524288ULL * 4, hipMemcpyDeviceToDevice, stream);
}